// Round 1
// baseline (1112.414 us; speedup 1.0000x reference)
//
#include <hip/hip_runtime.h>
#include <hip/hip_bf16.h>
#include <cstdint>

#define N_NODES 100000
#define HID 128

// ---------------- CSR build ----------------

__global__ __launch_bounds__(256) void hist_kernel(const int* __restrict__ dst, int* __restrict__ cnt, int E) {
    int i = blockIdx.x * 256 + threadIdx.x;
    if (i < E) atomicAdd(&cnt[dst[i]], 1);
}

// single-block hierarchical scan: cnt[i] (counts) -> offs[i] (exclusive), cnt[i] <- offs[i] (cursor copy)
__global__ __launch_bounds__(1024) void scan_kernel(int* __restrict__ cnt, int* __restrict__ offs, int N) {
    __shared__ int wsum[16];
    __shared__ int chunkTot;
    __shared__ int carryS;
    const int tid = threadIdx.x, lane = tid & 63, w = tid >> 6;
    if (tid == 0) carryS = 0;
    __syncthreads();
    for (int base = 0; base < N; base += 1024) {
        int i = base + tid;
        int v = (i < N) ? cnt[i] : 0;
        // wave inclusive scan
        int s = v;
        #pragma unroll
        for (int o = 1; o < 64; o <<= 1) {
            int t = __shfl_up(s, o, 64);
            if (lane >= o) s += t;
        }
        if (lane == 63) wsum[w] = s;
        __syncthreads();
        if (w == 0 && lane < 16) {
            int t = wsum[lane];
            int ss = t;
            #pragma unroll
            for (int o = 1; o < 16; o <<= 1) {
                int u = __shfl_up(ss, o, 64);
                if (lane >= o) ss += u;
            }
            wsum[lane] = ss - t;          // exclusive wave offset
            if (lane == 15) chunkTot = ss; // total of this chunk
        }
        __syncthreads();
        int excl = (s - v) + wsum[w] + carryS;
        if (i < N) { offs[i] = excl; cnt[i] = excl; }
        __syncthreads();
        if (tid == 0) carryS += chunkTot;
        __syncthreads();
    }
    if (threadIdx.x == 0) offs[N] = carryS;
}

__global__ __launch_bounds__(256) void scatter_kernel(const int* __restrict__ src, const int* __restrict__ dst,
                                                      int* __restrict__ cursor, int* __restrict__ esrc, int E) {
    int i = blockIdx.x * 256 + threadIdx.x;
    if (i < E) {
        int d = dst[i];
        int pos = atomicAdd(&cursor[d], 1);
        esrc[pos] = src[i];
    }
}

// ---------------- mean aggregation: one wave per node ----------------

__global__ __launch_bounds__(256) void agg_kernel(const float* __restrict__ h, const int* __restrict__ offs,
                                                  const int* __restrict__ esrc, float* __restrict__ mean) {
    const int wave = threadIdx.x >> 6;
    const int lane = threadIdx.x & 63;
    const int node = blockIdx.x * 4 + wave;
    const int beg = offs[node], end = offs[node + 1];
    float2 acc = make_float2(0.f, 0.f);
    for (int e = beg; e < end; ++e) {
        int s = esrc[e];
        float2 v = *(const float2*)(h + (size_t)s * HID + lane * 2);
        acc.x += v.x; acc.y += v.y;
    }
    int c = end - beg;
    float inv = 1.0f / (float)(c > 0 ? c : 1);
    *(float2*)(mean + (size_t)node * HID + lane * 2) = make_float2(acc.x * inv, acc.y * inv);
}

// ---------------- fused GEMM: out = relu(mean@Wl + h@Wr + b), score (+)= out @ Ws_slice ----------------
// writes output in-place over `mio` (the mean buffer)

#define TR 32

__global__ __launch_bounds__(256) void gemm_relu_score(
    float* __restrict__ mio, const float* __restrict__ h,
    const float* __restrict__ Wl, const float* __restrict__ Wr,
    const float* __restrict__ bias, const float* __restrict__ Wsl,
    float* __restrict__ score, const int accum)
{
    __shared__ float smM[TR][132];
    __shared__ float smH[TR][132];
    const int tid = threadIdx.x;
    const int rowBase = blockIdx.x * TR;

    for (int i = tid; i < TR * 32; i += 256) {
        int r = i >> 5, c = i & 31;
        *(float4*)&smM[r][c * 4] = *(const float4*)(mio + (size_t)(rowBase + r) * HID + c * 4);
        *(float4*)&smH[r][c * 4] = *(const float4*)(h   + (size_t)(rowBase + r) * HID + c * 4);
    }
    __syncthreads();

    const int cx = tid & 31;   // 4 cols: 4*cx..4*cx+3
    const int ry = tid >> 5;   // 4 rows: ry*4..ry*4+3
    float4 acc[4];
    #pragma unroll
    for (int rr = 0; rr < 4; rr++) acc[rr] = make_float4(0.f, 0.f, 0.f, 0.f);

    const float4* Wl4 = (const float4*)Wl;
    const float4* Wr4 = (const float4*)Wr;

    for (int k0 = 0; k0 < HID; k0 += 4) {
        float4 wl0 = Wl4[(k0 + 0) * 32 + cx];
        float4 wl1 = Wl4[(k0 + 1) * 32 + cx];
        float4 wl2 = Wl4[(k0 + 2) * 32 + cx];
        float4 wl3 = Wl4[(k0 + 3) * 32 + cx];
        float4 wr0 = Wr4[(k0 + 0) * 32 + cx];
        float4 wr1 = Wr4[(k0 + 1) * 32 + cx];
        float4 wr2 = Wr4[(k0 + 2) * 32 + cx];
        float4 wr3 = Wr4[(k0 + 3) * 32 + cx];
        #pragma unroll
        for (int rr = 0; rr < 4; rr++) {
            const int r = ry * 4 + rr;
            float4 m  = *(const float4*)&smM[r][k0];
            float4 hh = *(const float4*)&smH[r][k0];
            acc[rr].x += m.x*wl0.x + m.y*wl1.x + m.z*wl2.x + m.w*wl3.x
                       + hh.x*wr0.x + hh.y*wr1.x + hh.z*wr2.x + hh.w*wr3.x;
            acc[rr].y += m.x*wl0.y + m.y*wl1.y + m.z*wl2.y + m.w*wl3.y
                       + hh.x*wr0.y + hh.y*wr1.y + hh.z*wr2.y + hh.w*wr3.y;
            acc[rr].z += m.x*wl0.z + m.y*wl1.z + m.z*wl2.z + m.w*wl3.z
                       + hh.x*wr0.z + hh.y*wr1.z + hh.z*wr2.z + hh.w*wr3.z;
            acc[rr].w += m.x*wl0.w + m.y*wl1.w + m.z*wl2.w + m.w*wl3.w
                       + hh.x*wr0.w + hh.y*wr1.w + hh.z*wr2.w + hh.w*wr3.w;
        }
    }

    float4 b4  = ((const float4*)bias)[cx];
    float4 ws4 = ((const float4*)Wsl)[cx];
    #pragma unroll
    for (int rr = 0; rr < 4; rr++) {
        int r = rowBase + ry * 4 + rr;
        float4 o;
        o.x = fmaxf(acc[rr].x + b4.x, 0.f);
        o.y = fmaxf(acc[rr].y + b4.y, 0.f);
        o.z = fmaxf(acc[rr].z + b4.z, 0.f);
        o.w = fmaxf(acc[rr].w + b4.w, 0.f);
        *(float4*)(mio + (size_t)r * HID + cx * 4) = o;
        float p = o.x * ws4.x + o.y * ws4.y + o.z * ws4.z + o.w * ws4.w;
        #pragma unroll
        for (int m = 16; m >= 1; m >>= 1) p += __shfl_xor(p, m, 64);
        if (cx == 0) score[r] = accum ? (score[r] + p) : p;
    }
}

// ---------------- finalize ----------------

__global__ __launch_bounds__(256) void finalize_kernel(const float* __restrict__ rr, const float* __restrict__ score,
                                                       const float* __restrict__ bs, const float* __restrict__ alpha,
                                                       float* __restrict__ out, int N) {
    int i = blockIdx.x * 256 + threadIdx.x;
    if (i < N) {
        float a = 1.f / (1.f + __expf(-alpha[0]));
        out[i] = a * rr[i] + (1.f - a) * (score[i] + bs[0]);
    }
}

extern "C" void kernel_launch(void* const* d_in, const int* in_sizes, int n_in,
                              void* d_out, int out_size, void* d_ws, size_t ws_size,
                              hipStream_t stream) {
    const float* x     = (const float*)d_in[0];
    const int*   eidx  = (const int*)d_in[1];
    const float* rrs   = (const float*)d_in[2];
    const float* Wl0   = (const float*)d_in[3];
    const float* Wr0   = (const float*)d_in[4];
    const float* b0    = (const float*)d_in[5];
    const float* Wl1   = (const float*)d_in[6];
    const float* Wr1   = (const float*)d_in[7];
    const float* b1    = (const float*)d_in[8];
    const float* Wl2   = (const float*)d_in[9];
    const float* Wr2   = (const float*)d_in[10];
    const float* b2    = (const float*)d_in[11];
    const float* Ws    = (const float*)d_in[12];
    const float* bs    = (const float*)d_in[13];
    const float* alpha = (const float*)d_in[14];

    const int N = N_NODES;
    const int E = in_sizes[1] / 2;
    const int* src = eidx;
    const int* dst = eidx + E;

    uintptr_t p = (uintptr_t)d_ws;
    auto alloc = [&](size_t bytes) -> void* {
        p = (p + 255) & ~(uintptr_t)255;
        void* r = (void*)p;
        p += bytes;
        return r;
    };
    int*   cnt   = (int*)alloc((size_t)N * 4);        // counts -> cursor
    int*   offs  = (int*)alloc((size_t)(N + 1) * 4);
    int*   esrc  = (int*)alloc((size_t)E * 4);
    float* score = (float*)alloc((size_t)N * 4);
    float* bufA  = (float*)alloc((size_t)N * HID * 4);
    float* bufB  = (float*)alloc((size_t)N * HID * 4);

    // --- CSR build ---
    hipMemsetAsync(cnt, 0, (size_t)N * 4, stream);
    hist_kernel<<<(E + 255) / 256, 256, 0, stream>>>(dst, cnt, E);
    scan_kernel<<<1, 1024, 0, stream>>>(cnt, offs, N);
    scatter_kernel<<<(E + 255) / 256, 256, 0, stream>>>(src, dst, cnt, esrc, E);

    const int aggGrid  = N / 4;     // 25000
    const int gemmGrid = N / TR;    // 3125

    // --- layer 0: mean(x)->bufA ; h1 = gemm(bufA, x) -> bufA ; score = h1@Ws0 ---
    agg_kernel<<<aggGrid, 256, 0, stream>>>(x, offs, esrc, bufA);
    gemm_relu_score<<<gemmGrid, 256, 0, stream>>>(bufA, x, Wl0, Wr0, b0, Ws + 0 * HID, score, 0);

    // --- layer 1: mean(bufA)->bufB ; h2 = gemm(bufB, bufA) -> bufB ; score += h2@Ws1 ---
    agg_kernel<<<aggGrid, 256, 0, stream>>>(bufA, offs, esrc, bufB);
    gemm_relu_score<<<gemmGrid, 256, 0, stream>>>(bufB, bufA, Wl1, Wr1, b1, Ws + 1 * HID, score, 1);

    // --- layer 2: mean(bufB)->bufA ; h3 = gemm(bufA, bufB) -> bufA ; score += h3@Ws2 ---
    agg_kernel<<<aggGrid, 256, 0, stream>>>(bufB, offs, esrc, bufA);
    gemm_relu_score<<<gemmGrid, 256, 0, stream>>>(bufA, bufB, Wl2, Wr2, b2, Ws + 2 * HID, score, 1);

    finalize_kernel<<<(N + 255) / 256, 256, 0, stream>>>(rrs, score, bs, alpha, (float*)d_out, N);
}

// Round 2
// 480.429 us; speedup vs baseline: 2.3155x; 2.3155x over previous
//
#include <hip/hip_runtime.h>
#include <hip/hip_bf16.h>
#include <cstdint>

#define N_NODES 100000
#define HID 128

typedef __attribute__((ext_vector_type(8))) short short8v;
typedef __attribute__((ext_vector_type(4))) float floatx4;

__device__ __forceinline__ float bflo(unsigned v) { return __uint_as_float(v << 16); }
__device__ __forceinline__ float bfhi(unsigned v) { return __uint_as_float(v & 0xffff0000u); }
__device__ __forceinline__ unsigned short f2bf(float f) {
    unsigned u = __float_as_uint(f);
    unsigned r = (u + 0x7fffu + ((u >> 16) & 1u)) >> 16;
    return (unsigned short)r;
}

// ---------------- fp32 -> bf16 convert (x) ----------------
__global__ __launch_bounds__(256) void convx_kernel(const float* __restrict__ x,
                                                    unsigned short* __restrict__ xb, int total8) {
    int i = blockIdx.x * 256 + threadIdx.x;
    if (i >= total8) return;
    const float4* p = (const float4*)x + (size_t)i * 2;
    float4 a = p[0], b = p[1];
    uint4 o;
    o.x = f2bf(a.x) | ((unsigned)f2bf(a.y) << 16);
    o.y = f2bf(a.z) | ((unsigned)f2bf(a.w) << 16);
    o.z = f2bf(b.x) | ((unsigned)f2bf(b.y) << 16);
    o.w = f2bf(b.z) | ((unsigned)f2bf(b.w) << 16);
    *(uint4*)(xb + (size_t)i * 8) = o;
}

// ---------------- weight pack: fragment-ready bf16 layout ----------------
// chunk (L, t, s, c, g) holds W[s*32+g*8+i][c], i=0..7  (t: 0=Wl, 1=Wr)
__global__ __launch_bounds__(256) void packw_kernel(const float* __restrict__ Wl0, const float* __restrict__ Wr0,
                                                    const float* __restrict__ Wl1, const float* __restrict__ Wr1,
                                                    const float* __restrict__ Wl2, const float* __restrict__ Wr2,
                                                    unsigned short* __restrict__ Bp) {
    int idx = blockIdx.x * 256 + threadIdx.x;
    if (idx >= 12288) return;
    int g = idx & 3, c = (idx >> 2) & 127, s = (idx >> 9) & 3, t = (idx >> 11) & 1, L = idx >> 12;
    const float* W = (t == 0) ? (L == 0 ? Wl0 : (L == 1 ? Wl1 : Wl2))
                              : (L == 0 ? Wr0 : (L == 1 ? Wr1 : Wr2));
    int k0 = s * 32 + g * 8;
    uint4 o;
    o.x = f2bf(W[(k0 + 0) * 128 + c]) | ((unsigned)f2bf(W[(k0 + 1) * 128 + c]) << 16);
    o.y = f2bf(W[(k0 + 2) * 128 + c]) | ((unsigned)f2bf(W[(k0 + 3) * 128 + c]) << 16);
    o.z = f2bf(W[(k0 + 4) * 128 + c]) | ((unsigned)f2bf(W[(k0 + 5) * 128 + c]) << 16);
    o.w = f2bf(W[(k0 + 6) * 128 + c]) | ((unsigned)f2bf(W[(k0 + 7) * 128 + c]) << 16);
    size_t chunk = (((size_t)(L * 2 + t) * 4 + s) * 128 + c) * 4 + g;
    *(uint4*)(Bp + chunk * 8) = o;
}

// ---------------- CSR build ----------------
__global__ __launch_bounds__(256) void hist_kernel(const int* __restrict__ dst, int* __restrict__ cnt, int E) {
    int i = blockIdx.x * 256 + threadIdx.x;
    if (i < E) atomicAdd(&cnt[dst[i]], 1);
}

__global__ __launch_bounds__(1024) void reduce_kernel(const int* __restrict__ cnt, int* __restrict__ bsum, int N) {
    __shared__ int ws[16];
    int tid = threadIdx.x;
    int i = blockIdx.x * 1024 + tid;
    int v = (i < N) ? cnt[i] : 0;
    #pragma unroll
    for (int o = 32; o >= 1; o >>= 1) v += __shfl_xor(v, o, 64);
    if ((tid & 63) == 0) ws[tid >> 6] = v;
    __syncthreads();
    if (tid < 16) {
        int t = ws[tid];
        #pragma unroll
        for (int o = 8; o >= 1; o >>= 1) t += __shfl_xor(t, o, 64);
        if (tid == 0) bsum[blockIdx.x] = t;
    }
}

__global__ __launch_bounds__(128) void scanp_kernel(int* __restrict__ bsum, int nb) {
    __shared__ int tmp[128];
    int tid = threadIdx.x;
    int v = (tid < nb) ? bsum[tid] : 0;
    tmp[tid] = v;
    __syncthreads();
    int acc = v;
    for (int o = 1; o < 128; o <<= 1) {
        int t = (tid >= o) ? tmp[tid - o] : 0;
        __syncthreads();
        acc += t;
        tmp[tid] = acc;
        __syncthreads();
    }
    if (tid < nb) bsum[tid] = acc - v;   // exclusive
}

__global__ __launch_bounds__(1024) void scanf_kernel(int* __restrict__ cnt, const int* __restrict__ bsum,
                                                     int* __restrict__ offs, int N, int E) {
    __shared__ int wsum[16];
    int tid = threadIdx.x, lane = tid & 63, w = tid >> 6;
    int i = blockIdx.x * 1024 + tid;
    int v = (i < N) ? cnt[i] : 0;
    int s = v;
    #pragma unroll
    for (int o = 1; o < 64; o <<= 1) {
        int t = __shfl_up(s, o, 64);
        if (lane >= o) s += t;
    }
    if (lane == 63) wsum[w] = s;
    __syncthreads();
    if (w == 0 && lane < 16) {
        int t = wsum[lane];
        int ss = t;
        #pragma unroll
        for (int o = 1; o < 16; o <<= 1) {
            int u = __shfl_up(ss, o, 64);
            if (lane >= o) ss += u;
        }
        wsum[lane] = ss - t;
    }
    __syncthreads();
    int excl = (s - v) + wsum[w] + bsum[blockIdx.x];
    if (i < N) { offs[i] = excl; cnt[i] = excl; }
    if (blockIdx.x == 0 && tid == 0) offs[N] = E;
}

__global__ __launch_bounds__(256) void scatter_kernel(const int* __restrict__ src, const int* __restrict__ dst,
                                                      int* __restrict__ cursor, int* __restrict__ esrc, int E) {
    int i = blockIdx.x * 256 + threadIdx.x;
    if (i < E) {
        int d = dst[i];
        int pos = atomicAdd(&cursor[d], 1);
        esrc[pos] = src[i];
    }
}

// ---------------- mean aggregation (bf16 rows, fp32 accumulate) ----------------
__global__ __launch_bounds__(256) void agg_kernel(const unsigned short* __restrict__ h,
                                                  const int* __restrict__ offs,
                                                  const int* __restrict__ esrc,
                                                  unsigned short* __restrict__ mean) {
    const int lane = threadIdx.x & 63;
    const int node = blockIdx.x * 4 + (threadIdx.x >> 6);
    const int beg = offs[node], end = offs[node + 1];
    const int nb = end - beg;
    float ax = 0.f, ay = 0.f;
    for (int base = 0; base < nb; base += 64) {
        int m = nb - base; if (m > 64) m = 64;
        int sv = (lane < m) ? esrc[beg + base + lane] : 0;
        int j = 0;
        for (; j + 4 <= m; j += 4) {
            int s0 = __shfl(sv, j, 64), s1 = __shfl(sv, j + 1, 64);
            int s2 = __shfl(sv, j + 2, 64), s3 = __shfl(sv, j + 3, 64);
            unsigned v0 = *(const unsigned*)(h + (size_t)s0 * HID + lane * 2);
            unsigned v1 = *(const unsigned*)(h + (size_t)s1 * HID + lane * 2);
            unsigned v2 = *(const unsigned*)(h + (size_t)s2 * HID + lane * 2);
            unsigned v3 = *(const unsigned*)(h + (size_t)s3 * HID + lane * 2);
            ax += bflo(v0) + bflo(v1) + bflo(v2) + bflo(v3);
            ay += bfhi(v0) + bfhi(v1) + bfhi(v2) + bfhi(v3);
        }
        for (; j < m; ++j) {
            int s0 = __shfl(sv, j, 64);
            unsigned v0 = *(const unsigned*)(h + (size_t)s0 * HID + lane * 2);
            ax += bflo(v0); ay += bfhi(v0);
        }
    }
    float inv = 1.f / (float)(nb > 0 ? nb : 1);
    *(unsigned*)(mean + (size_t)node * HID + lane * 2) =
        (unsigned)f2bf(ax * inv) | ((unsigned)f2bf(ay * inv) << 16);
}

// ---------------- MFMA GEMM: out = relu([mean|h]@[Wl;Wr] + b); score (+)= out@Wsl ----------------
// block: 64 rows x 128 cols, 4 waves (wm = w&1 -> 32-row half, wn = w>>1 -> 64-col half)
__global__ __launch_bounds__(256) void gemm_kernel(const unsigned short* __restrict__ Am,
                                                   const unsigned short* __restrict__ Ah,
                                                   const unsigned short* __restrict__ Bp,
                                                   const float* __restrict__ bias,
                                                   const float* __restrict__ Wsl,
                                                   unsigned short* __restrict__ hout,
                                                   float* __restrict__ score,
                                                   const int accum, const int writeH) {
    __shared__ unsigned short At[2 * 64 * 128];   // 32 KB, 16B-chunk swizzled
    __shared__ float sred[2][64];
    const int tid = threadIdx.x;
    const int lane = tid & 63;
    const int w = tid >> 6;
    const int wm = w & 1, wn = w >> 1;
    const int rowBase = blockIdx.x * 64;
    const int halfRow = lane & 15;
    const int g = lane >> 4;

    // stage A tiles (mean, h) via global_load_lds; source pre-swizzled: slot' = slot ^ (row&15)
    {
        const unsigned short* srcs[2] = { Am, Ah };
        #pragma unroll
        for (int r = 0; r < 8; ++r) {
            int c = r * 256 + tid;
            int sIdx = c >> 10;
            int rem = c & 1023;
            int row = rem >> 4, slot = rem & 15;
            int gslot = slot ^ (row & 15);
            int grow = rowBase + row; if (grow >= N_NODES) grow = N_NODES - 1;
            const unsigned short* gp = srcs[sIdx] + (size_t)grow * HID + gslot * 8;
            unsigned ldsOff = (unsigned)(r * 4096 + w * 1024);
            __builtin_amdgcn_global_load_lds((const __attribute__((address_space(1))) void*)gp,
                                             (__attribute__((address_space(3))) void*)((char*)At + ldsOff),
                                             16, 0, 0);
        }
    }
    __syncthreads();

    floatx4 acc[2][4];
    #pragma unroll
    for (int m = 0; m < 2; m++)
        #pragma unroll
        for (int n = 0; n < 4; n++) acc[m][n] = (floatx4){0.f, 0.f, 0.f, 0.f};

    #pragma unroll
    for (int t = 0; t < 2; t++) {
        #pragma unroll
        for (int s = 0; s < 4; s++) {
            int slot = (s * 4 + g) ^ halfRow;
            int row0 = wm * 32 + halfRow;
            short8v a0 = *(const short8v*)&At[t * 8192 + row0 * 128 + slot * 8];
            short8v a1 = *(const short8v*)&At[t * 8192 + (row0 + 16) * 128 + slot * 8];
            #pragma unroll
            for (int n = 0; n < 4; n++) {
                int col = wn * 64 + n * 16 + halfRow;
                short8v b = *(const short8v*)&Bp[((((size_t)(t * 4 + s)) * 128 + col) * 4 + g) * 8];
                acc[0][n] = __builtin_amdgcn_mfma_f32_16x16x32_bf16(a0, b, acc[0][n], 0, 0, 0);
                acc[1][n] = __builtin_amdgcn_mfma_f32_16x16x32_bf16(a1, b, acc[1][n], 0, 0, 0);
            }
        }
    }

    // epilogue: bias + ReLU + bf16 store + per-row score partial
    #pragma unroll
    for (int m = 0; m < 2; m++) {
        #pragma unroll
        for (int i = 0; i < 4; i++) {
            int rloc = wm * 32 + m * 16 + g * 4 + i;
            int grow = rowBase + rloc;
            float ps = 0.f;
            #pragma unroll
            for (int n = 0; n < 4; n++) {
                int col = wn * 64 + n * 16 + halfRow;
                float v = acc[m][n][i] + bias[col];
                v = fmaxf(v, 0.f);
                if (writeH && grow < N_NODES) hout[(size_t)grow * HID + col] = f2bf(v);
                ps += v * Wsl[col];
            }
            ps += __shfl_xor(ps, 1, 64);
            ps += __shfl_xor(ps, 2, 64);
            ps += __shfl_xor(ps, 4, 64);
            ps += __shfl_xor(ps, 8, 64);
            if (halfRow == 0) sred[wn][rloc] = ps;
        }
    }
    __syncthreads();
    if (w == 0) {
        int grow = rowBase + lane;
        if (grow < N_NODES) {
            float tot = sred[0][lane] + sred[1][lane];
            score[grow] = accum ? (score[grow] + tot) : tot;
        }
    }
}

// ---------------- finalize ----------------
__global__ __launch_bounds__(256) void finalize_kernel(const float* __restrict__ rr, const float* __restrict__ score,
                                                       const float* __restrict__ bs, const float* __restrict__ alpha,
                                                       float* __restrict__ out, int N) {
    int i = blockIdx.x * 256 + threadIdx.x;
    if (i < N) {
        float a = 1.f / (1.f + __expf(-alpha[0]));
        out[i] = a * rr[i] + (1.f - a) * (score[i] + bs[0]);
    }
}

extern "C" void kernel_launch(void* const* d_in, const int* in_sizes, int n_in,
                              void* d_out, int out_size, void* d_ws, size_t ws_size,
                              hipStream_t stream) {
    const float* x     = (const float*)d_in[0];
    const int*   eidx  = (const int*)d_in[1];
    const float* rrs   = (const float*)d_in[2];
    const float* Wl0   = (const float*)d_in[3];
    const float* Wr0   = (const float*)d_in[4];
    const float* b0    = (const float*)d_in[5];
    const float* Wl1   = (const float*)d_in[6];
    const float* Wr1   = (const float*)d_in[7];
    const float* b1    = (const float*)d_in[8];
    const float* Wl2   = (const float*)d_in[9];
    const float* Wr2   = (const float*)d_in[10];
    const float* b2    = (const float*)d_in[11];
    const float* Ws    = (const float*)d_in[12];
    const float* bs    = (const float*)d_in[13];
    const float* alpha = (const float*)d_in[14];

    const int N = N_NODES;
    const int E = in_sizes[1] / 2;
    const int* src = eidx;
    const int* dst = eidx + E;

    uintptr_t p = (uintptr_t)d_ws;
    auto alloc = [&](size_t bytes) -> void* {
        p = (p + 255) & ~(uintptr_t)255;
        void* r = (void*)p;
        p += bytes;
        return r;
    };
    int*            cnt   = (int*)alloc((size_t)N * 4);
    int*            offs  = (int*)alloc((size_t)(N + 1) * 4);
    int*            esrc  = (int*)alloc((size_t)E * 4);
    float*          score = (float*)alloc((size_t)N * 4);
    int*            bsum  = (int*)alloc(512);
    unsigned short* xb    = (unsigned short*)alloc((size_t)N * HID * 2);
    unsigned short* bufA  = (unsigned short*)alloc((size_t)N * HID * 2);
    unsigned short* bufB  = (unsigned short*)alloc((size_t)N * HID * 2);
    unsigned short* Bp    = (unsigned short*)alloc((size_t)3 * 32768 * 2);

    // conversions
    convx_kernel<<<6250, 256, 0, stream>>>(x, xb, N * HID / 8);
    packw_kernel<<<48, 256, 0, stream>>>(Wl0, Wr0, Wl1, Wr1, Wl2, Wr2, Bp);

    // CSR build
    hipMemsetAsync(cnt, 0, (size_t)N * 4, stream);
    hist_kernel<<<(E + 255) / 256, 256, 0, stream>>>(dst, cnt, E);
    const int nb = (N + 1023) / 1024;   // 98
    reduce_kernel<<<nb, 1024, 0, stream>>>(cnt, bsum, N);
    scanp_kernel<<<1, 128, 0, stream>>>(bsum, nb);
    scanf_kernel<<<nb, 1024, 0, stream>>>(cnt, bsum, offs, N, E);
    scatter_kernel<<<(E + 255) / 256, 256, 0, stream>>>(src, dst, cnt, esrc, E);

    const int aggGrid  = N / 4;            // 25000
    const int gemmGrid = (N + 63) / 64;    // 1563

    // layer 0
    agg_kernel<<<aggGrid, 256, 0, stream>>>(xb, offs, esrc, bufA);
    gemm_kernel<<<gemmGrid, 256, 0, stream>>>(bufA, xb, Bp + 0 * 32768, b0, Ws + 0 * HID, bufA, score, 0, 1);
    // layer 1
    agg_kernel<<<aggGrid, 256, 0, stream>>>(bufA, offs, esrc, bufB);
    gemm_kernel<<<gemmGrid, 256, 0, stream>>>(bufB, bufA, Bp + 1 * 32768, b1, Ws + 1 * HID, bufB, score, 1, 1);
    // layer 2
    agg_kernel<<<aggGrid, 256, 0, stream>>>(bufB, offs, esrc, bufA);
    gemm_kernel<<<gemmGrid, 256, 0, stream>>>(bufA, bufB, Bp + 2 * 32768, b2, Ws + 2 * HID, bufA, score, 1, 0);

    finalize_kernel<<<(N + 255) / 256, 256, 0, stream>>>(rrs, score, bs, alpha, (float*)d_out, N);
}

// Round 3
// 428.657 us; speedup vs baseline: 2.5951x; 1.1208x over previous
//
#include <hip/hip_runtime.h>
#include <hip/hip_bf16.h>
#include <cstdint>

#define N_NODES 100000
#define HID 128
#define NBINS 391            // ceil(100000/256)
#define CHUNK 4096

typedef __attribute__((ext_vector_type(8))) short short8v;
typedef __attribute__((ext_vector_type(4))) float floatx4;

__device__ __forceinline__ float bflo(unsigned v) { return __uint_as_float(v << 16); }
__device__ __forceinline__ float bfhi(unsigned v) { return __uint_as_float(v & 0xffff0000u); }
__device__ __forceinline__ unsigned short f2bf(float f) {
    unsigned u = __float_as_uint(f);
    unsigned r = (u + 0x7fffu + ((u >> 16) & 1u)) >> 16;
    return (unsigned short)r;
}

// ---------------- fp32 -> bf16 convert (x) ----------------
__global__ __launch_bounds__(256) void convx_kernel(const float* __restrict__ x,
                                                    unsigned short* __restrict__ xb, int total8) {
    int i = blockIdx.x * 256 + threadIdx.x;
    if (i >= total8) return;
    const float4* p = (const float4*)x + (size_t)i * 2;
    float4 a = p[0], b = p[1];
    uint4 o;
    o.x = f2bf(a.x) | ((unsigned)f2bf(a.y) << 16);
    o.y = f2bf(a.z) | ((unsigned)f2bf(a.w) << 16);
    o.z = f2bf(b.x) | ((unsigned)f2bf(b.y) << 16);
    o.w = f2bf(b.z) | ((unsigned)f2bf(b.w) << 16);
    *(uint4*)(xb + (size_t)i * 8) = o;
}

// ---------------- weight pack: fragment-ready bf16 layout ----------------
__global__ __launch_bounds__(256) void packw_kernel(const float* __restrict__ Wl0, const float* __restrict__ Wr0,
                                                    const float* __restrict__ Wl1, const float* __restrict__ Wr1,
                                                    const float* __restrict__ Wl2, const float* __restrict__ Wr2,
                                                    unsigned short* __restrict__ Bp) {
    int idx = blockIdx.x * 256 + threadIdx.x;
    if (idx >= 12288) return;
    int g = idx & 3, c = (idx >> 2) & 127, s = (idx >> 9) & 3, t = (idx >> 11) & 1, L = idx >> 12;
    const float* W = (t == 0) ? (L == 0 ? Wl0 : (L == 1 ? Wl1 : Wl2))
                              : (L == 0 ? Wr0 : (L == 1 ? Wr1 : Wr2));
    int k0 = s * 32 + g * 8;
    uint4 o;
    o.x = f2bf(W[(k0 + 0) * 128 + c]) | ((unsigned)f2bf(W[(k0 + 1) * 128 + c]) << 16);
    o.y = f2bf(W[(k0 + 2) * 128 + c]) | ((unsigned)f2bf(W[(k0 + 3) * 128 + c]) << 16);
    o.z = f2bf(W[(k0 + 4) * 128 + c]) | ((unsigned)f2bf(W[(k0 + 5) * 128 + c]) << 16);
    o.w = f2bf(W[(k0 + 6) * 128 + c]) | ((unsigned)f2bf(W[(k0 + 7) * 128 + c]) << 16);
    size_t chunk = (((size_t)(L * 2 + t) * 4 + s) * 128 + c) * 4 + g;
    *(uint4*)(Bp + chunk * 8) = o;
}

// ---------------- CSR build: atomic-free bucket sort ----------------

// A1: per-chunk bin histogram -> cntMat[chunk][bin]
__global__ __launch_bounds__(256) void binhist_kernel(const int* __restrict__ dst,
                                                      int* __restrict__ cntMat, int E) {
    __shared__ int lcnt[512];
    const int tid = threadIdx.x;
    lcnt[tid] = 0; lcnt[tid + 256] = 0;
    __syncthreads();
    int base = blockIdx.x * CHUNK;
    int end = base + CHUNK; if (end > E) end = E;
    for (int i = base + tid; i < end; i += 256) atomicAdd(&lcnt[dst[i] >> 8], 1);
    __syncthreads();
    for (int j = tid; j < NBINS; j += 256) cntMat[(size_t)blockIdx.x * NBINS + j] = lcnt[j];
}

// A2: column prefix (over chunks) + bin exclusive scan; cntMat becomes global start offsets
__global__ __launch_bounds__(1024) void binscan_kernel(int* __restrict__ cntMat,
                                                       int* __restrict__ binBase, int* __restrict__ binCnt,
                                                       int* __restrict__ offs, int nch, int E) {
    __shared__ int tot[512];
    __shared__ int sc[512];
    const int tid = threadIdx.x;
    int orig = 0;
    if (tid < NBINS) {
        int run = 0;
        for (int b = 0; b < nch; ++b) {
            size_t idx = (size_t)b * NBINS + tid;
            int v = cntMat[idx];
            cntMat[idx] = run;
            run += v;
        }
        orig = run;
        tot[tid] = run;
    } else if (tid < 512) {
        tot[tid] = 0;
    }
    __syncthreads();
    // inclusive scan over 512
    for (int o = 1; o < 512; o <<= 1) {
        int t = 0;
        if (tid < 512 && tid >= o) t = tot[tid - o];
        __syncthreads();
        if (tid < 512) tot[tid] += t;
        __syncthreads();
    }
    int excl = 0;
    if (tid < 512) excl = tot[tid] - orig;
    if (tid < NBINS) {
        binBase[tid] = excl;
        binCnt[tid] = orig;
        sc[tid] = excl;
    }
    __syncthreads();
    size_t total = (size_t)nch * NBINS;
    for (size_t idx = tid; idx < total; idx += 1024) {
        int j = (int)(idx % NBINS);
        cntMat[idx] += sc[j];
    }
    if (tid == 0) offs[N_NODES] = E;
}

// A3: scatter edges into bin regions (packed src | dstLow<<20)
__global__ __launch_bounds__(256) void binscat_kernel(const int* __restrict__ src, const int* __restrict__ dst,
                                                      const int* __restrict__ cntMat,
                                                      unsigned* __restrict__ binned, int E) {
    __shared__ int cur[512];
    const int tid = threadIdx.x;
    const int row = blockIdx.x;
    for (int j = tid; j < NBINS; j += 256) cur[j] = cntMat[(size_t)row * NBINS + j];
    __syncthreads();
    int base = row * CHUNK;
    int end = base + CHUNK; if (end > E) end = E;
    for (int i = base + tid; i < end; i += 256) {
        int d = dst[i];
        int s = src[i];
        int bin = d >> 8;
        int pos = atomicAdd(&cur[bin], 1);
        binned[pos] = (unsigned)s | ((unsigned)(d & 255) << 20);
    }
}

// B: per-bin CSR finalize: offs + dst-sorted esrc (LDS-staged, coalesced out)
__global__ __launch_bounds__(256) void bincsr_kernel(const unsigned* __restrict__ binned,
                                                     const int* __restrict__ binBase, const int* __restrict__ binCnt,
                                                     int* __restrict__ esrc, int* __restrict__ offs) {
    __shared__ int h[256];
    __shared__ int cur[256];
    __shared__ int ssrc[8192];
    const int tid = threadIdx.x;
    const int bin = blockIdx.x;
    const int base = binBase[bin];
    const int cnt = binCnt[bin];
    h[tid] = 0;
    __syncthreads();
    for (int i = tid; i < cnt; i += 256) atomicAdd(&h[binned[base + i] >> 20], 1);
    __syncthreads();
    int v = h[tid];
    for (int o = 1; o < 256; o <<= 1) {
        int t = (tid >= o) ? h[tid - o] : 0;
        __syncthreads();
        h[tid] += t;
        __syncthreads();
    }
    int excl = h[tid] - v;
    cur[tid] = excl;
    int node = (bin << 8) + tid;
    if (node < N_NODES) offs[node] = base + excl;
    __syncthreads();
    for (int i = tid; i < cnt; i += 256) {
        unsigned p = binned[base + i];
        int pos = atomicAdd(&cur[p >> 20], 1);
        int s = (int)(p & 0xFFFFFu);
        if (pos < 8192) ssrc[pos] = s;
        else esrc[base + pos] = s;   // overflow fallback (never hit for uniform graph)
    }
    __syncthreads();
    int lim = cnt < 8192 ? cnt : 8192;
    for (int i = tid; i < lim; i += 256) esrc[base + i] = ssrc[i];
}

// ---------------- mean aggregation (bf16 rows, fp32 accumulate) ----------------
__global__ __launch_bounds__(256) void agg_kernel(const unsigned short* __restrict__ h,
                                                  const int* __restrict__ offs,
                                                  const int* __restrict__ esrc,
                                                  unsigned short* __restrict__ mean) {
    const int lane = threadIdx.x & 63;
    const int node = blockIdx.x * 4 + (threadIdx.x >> 6);
    const int beg = offs[node], end = offs[node + 1];
    const int nb = end - beg;
    float ax = 0.f, ay = 0.f;
    for (int base = 0; base < nb; base += 64) {
        int m = nb - base; if (m > 64) m = 64;
        int sv = (lane < m) ? esrc[beg + base + lane] : 0;
        int j = 0;
        for (; j + 4 <= m; j += 4) {
            int s0 = __shfl(sv, j, 64), s1 = __shfl(sv, j + 1, 64);
            int s2 = __shfl(sv, j + 2, 64), s3 = __shfl(sv, j + 3, 64);
            unsigned v0 = *(const unsigned*)(h + (size_t)s0 * HID + lane * 2);
            unsigned v1 = *(const unsigned*)(h + (size_t)s1 * HID + lane * 2);
            unsigned v2 = *(const unsigned*)(h + (size_t)s2 * HID + lane * 2);
            unsigned v3 = *(const unsigned*)(h + (size_t)s3 * HID + lane * 2);
            ax += bflo(v0) + bflo(v1) + bflo(v2) + bflo(v3);
            ay += bfhi(v0) + bfhi(v1) + bfhi(v2) + bfhi(v3);
        }
        for (; j < m; ++j) {
            int s0 = __shfl(sv, j, 64);
            unsigned v0 = *(const unsigned*)(h + (size_t)s0 * HID + lane * 2);
            ax += bflo(v0); ay += bfhi(v0);
        }
    }
    float inv = 1.f / (float)(nb > 0 ? nb : 1);
    *(unsigned*)(mean + (size_t)node * HID + lane * 2) =
        (unsigned)f2bf(ax * inv) | ((unsigned)f2bf(ay * inv) << 16);
}

// ---------------- MFMA GEMM: out = relu([mean|h]@[Wl;Wr] + b); score (+)= out@Wsl ----------------
__global__ __launch_bounds__(256) void gemm_kernel(const unsigned short* __restrict__ Am,
                                                   const unsigned short* __restrict__ Ah,
                                                   const unsigned short* __restrict__ Bp,
                                                   const float* __restrict__ bias,
                                                   const float* __restrict__ Wsl,
                                                   unsigned short* __restrict__ hout,
                                                   float* __restrict__ score,
                                                   const int accum, const int writeH) {
    __shared__ unsigned short At[2 * 64 * 128];
    __shared__ float sred[2][64];
    const int tid = threadIdx.x;
    const int lane = tid & 63;
    const int w = tid >> 6;
    const int wm = w & 1, wn = w >> 1;
    const int rowBase = blockIdx.x * 64;
    const int halfRow = lane & 15;
    const int g = lane >> 4;

    {
        const unsigned short* srcs[2] = { Am, Ah };
        #pragma unroll
        for (int r = 0; r < 8; ++r) {
            int c = r * 256 + tid;
            int sIdx = c >> 10;
            int rem = c & 1023;
            int row = rem >> 4, slot = rem & 15;
            int gslot = slot ^ (row & 15);
            int grow = rowBase + row; if (grow >= N_NODES) grow = N_NODES - 1;
            const unsigned short* gp = srcs[sIdx] + (size_t)grow * HID + gslot * 8;
            unsigned ldsOff = (unsigned)(r * 4096 + w * 1024);
            __builtin_amdgcn_global_load_lds((const __attribute__((address_space(1))) void*)gp,
                                             (__attribute__((address_space(3))) void*)((char*)At + ldsOff),
                                             16, 0, 0);
        }
    }
    __syncthreads();

    floatx4 acc[2][4];
    #pragma unroll
    for (int m = 0; m < 2; m++)
        #pragma unroll
        for (int n = 0; n < 4; n++) acc[m][n] = (floatx4){0.f, 0.f, 0.f, 0.f};

    #pragma unroll
    for (int t = 0; t < 2; t++) {
        #pragma unroll
        for (int s = 0; s < 4; s++) {
            int slot = (s * 4 + g) ^ halfRow;
            int row0 = wm * 32 + halfRow;
            short8v a0 = *(const short8v*)&At[t * 8192 + row0 * 128 + slot * 8];
            short8v a1 = *(const short8v*)&At[t * 8192 + (row0 + 16) * 128 + slot * 8];
            #pragma unroll
            for (int n = 0; n < 4; n++) {
                int col = wn * 64 + n * 16 + halfRow;
                short8v b = *(const short8v*)&Bp[((((size_t)(t * 4 + s)) * 128 + col) * 4 + g) * 8];
                acc[0][n] = __builtin_amdgcn_mfma_f32_16x16x32_bf16(a0, b, acc[0][n], 0, 0, 0);
                acc[1][n] = __builtin_amdgcn_mfma_f32_16x16x32_bf16(a1, b, acc[1][n], 0, 0, 0);
            }
        }
    }

    #pragma unroll
    for (int m = 0; m < 2; m++) {
        #pragma unroll
        for (int i = 0; i < 4; i++) {
            int rloc = wm * 32 + m * 16 + g * 4 + i;
            int grow = rowBase + rloc;
            float ps = 0.f;
            #pragma unroll
            for (int n = 0; n < 4; n++) {
                int col = wn * 64 + n * 16 + halfRow;
                float v = acc[m][n][i] + bias[col];
                v = fmaxf(v, 0.f);
                if (writeH && grow < N_NODES) hout[(size_t)grow * HID + col] = f2bf(v);
                ps += v * Wsl[col];
            }
            ps += __shfl_xor(ps, 1, 64);
            ps += __shfl_xor(ps, 2, 64);
            ps += __shfl_xor(ps, 4, 64);
            ps += __shfl_xor(ps, 8, 64);
            if (halfRow == 0) sred[wn][rloc] = ps;
        }
    }
    __syncthreads();
    if (w == 0) {
        int grow = rowBase + lane;
        if (grow < N_NODES) {
            float tot = sred[0][lane] + sred[1][lane];
            score[grow] = accum ? (score[grow] + tot) : tot;
        }
    }
}

// ---------------- finalize ----------------
__global__ __launch_bounds__(256) void finalize_kernel(const float* __restrict__ rr, const float* __restrict__ score,
                                                       const float* __restrict__ bs, const float* __restrict__ alpha,
                                                       float* __restrict__ out, int N) {
    int i = blockIdx.x * 256 + threadIdx.x;
    if (i < N) {
        float a = 1.f / (1.f + __expf(-alpha[0]));
        out[i] = a * rr[i] + (1.f - a) * (score[i] + bs[0]);
    }
}

extern "C" void kernel_launch(void* const* d_in, const int* in_sizes, int n_in,
                              void* d_out, int out_size, void* d_ws, size_t ws_size,
                              hipStream_t stream) {
    const float* x     = (const float*)d_in[0];
    const int*   eidx  = (const int*)d_in[1];
    const float* rrs   = (const float*)d_in[2];
    const float* Wl0   = (const float*)d_in[3];
    const float* Wr0   = (const float*)d_in[4];
    const float* b0    = (const float*)d_in[5];
    const float* Wl1   = (const float*)d_in[6];
    const float* Wr1   = (const float*)d_in[7];
    const float* b1    = (const float*)d_in[8];
    const float* Wl2   = (const float*)d_in[9];
    const float* Wr2   = (const float*)d_in[10];
    const float* b2    = (const float*)d_in[11];
    const float* Ws    = (const float*)d_in[12];
    const float* bs    = (const float*)d_in[13];
    const float* alpha = (const float*)d_in[14];

    const int N = N_NODES;
    const int E = in_sizes[1] / 2;
    const int* src = eidx;
    const int* dst = eidx + E;

    uintptr_t p = (uintptr_t)d_ws;
    auto alloc = [&](size_t bytes) -> void* {
        p = (p + 255) & ~(uintptr_t)255;
        void* r = (void*)p;
        p += bytes;
        return r;
    };
    int*            offs    = (int*)alloc((size_t)(N + 1) * 4);
    int*            esrc    = (int*)alloc((size_t)E * 4);
    float*          score   = (float*)alloc((size_t)N * 4);
    int*            binBase = (int*)alloc(512 * 4);
    int*            binCnt  = (int*)alloc(512 * 4);
    unsigned short* xb      = (unsigned short*)alloc((size_t)N * HID * 2);
    unsigned short* bufA    = (unsigned short*)alloc((size_t)N * HID * 2);
    unsigned short* bufB    = (unsigned short*)alloc((size_t)N * HID * 2);
    unsigned short* Bp      = (unsigned short*)alloc((size_t)3 * 32768 * 2);

    // dead-region aliases during CSR build (consumed before bufA/bufB are first written)
    int*      cntMat = (int*)bufA;        // nch*NBINS ints  (~612 KB)
    unsigned* binned = (unsigned*)bufB;   // E unsigneds     (6.4 MB)

    const int nch = (E + CHUNK - 1) / CHUNK;

    // conversions
    convx_kernel<<<6250, 256, 0, stream>>>(x, xb, N * HID / 8);
    packw_kernel<<<48, 256, 0, stream>>>(Wl0, Wr0, Wl1, Wr1, Wl2, Wr2, Bp);

    // CSR build (atomic-free bucket sort)
    binhist_kernel<<<nch, 256, 0, stream>>>(dst, cntMat, E);
    binscan_kernel<<<1, 1024, 0, stream>>>(cntMat, binBase, binCnt, offs, nch, E);
    binscat_kernel<<<nch, 256, 0, stream>>>(src, dst, cntMat, binned, E);
    bincsr_kernel<<<NBINS, 256, 0, stream>>>(binned, binBase, binCnt, esrc, offs);

    const int aggGrid  = N / 4;            // 25000
    const int gemmGrid = (N + 63) / 64;    // 1563

    // layer 0
    agg_kernel<<<aggGrid, 256, 0, stream>>>(xb, offs, esrc, bufA);
    gemm_kernel<<<gemmGrid, 256, 0, stream>>>(bufA, xb, Bp + 0 * 32768, b0, Ws + 0 * HID, bufA, score, 0, 1);
    // layer 1
    agg_kernel<<<aggGrid, 256, 0, stream>>>(bufA, offs, esrc, bufB);
    gemm_kernel<<<gemmGrid, 256, 0, stream>>>(bufB, bufA, Bp + 1 * 32768, b1, Ws + 1 * HID, bufB, score, 1, 1);
    // layer 2
    agg_kernel<<<aggGrid, 256, 0, stream>>>(bufB, offs, esrc, bufA);
    gemm_kernel<<<gemmGrid, 256, 0, stream>>>(bufA, bufB, Bp + 2 * 32768, b2, Ws + 2 * HID, bufA, score, 1, 0);

    finalize_kernel<<<(N + 255) / 256, 256, 0, stream>>>(rrs, score, bs, alpha, (float*)d_out, N);
}

// Round 4
// 318.736 us; speedup vs baseline: 3.4901x; 1.3449x over previous
//
#include <hip/hip_runtime.h>
#include <hip/hip_bf16.h>
#include <cstdint>

#define N_NODES 100000
#define HID 128
#define NBINS 391            // ceil(100000/256)
#define CHUNK 4096

typedef __attribute__((ext_vector_type(8))) short short8v;
typedef __attribute__((ext_vector_type(4))) float floatx4;

__device__ __forceinline__ float bflo(unsigned v) { return __uint_as_float(v << 16); }
__device__ __forceinline__ float bfhi(unsigned v) { return __uint_as_float(v & 0xffff0000u); }
__device__ __forceinline__ unsigned short f2bf(float f) {
    unsigned u = __float_as_uint(f);
    unsigned r = (u + 0x7fffu + ((u >> 16) & 1u)) >> 16;
    return (unsigned short)r;
}

// ---------------- fp32 -> bf16 convert (x) ----------------
__global__ __launch_bounds__(256) void convx_kernel(const float* __restrict__ x,
                                                    unsigned short* __restrict__ xb, int total8) {
    int i = blockIdx.x * 256 + threadIdx.x;
    if (i >= total8) return;
    const float4* p = (const float4*)x + (size_t)i * 2;
    float4 a = p[0], b = p[1];
    uint4 o;
    o.x = f2bf(a.x) | ((unsigned)f2bf(a.y) << 16);
    o.y = f2bf(a.z) | ((unsigned)f2bf(a.w) << 16);
    o.z = f2bf(b.x) | ((unsigned)f2bf(b.y) << 16);
    o.w = f2bf(b.z) | ((unsigned)f2bf(b.w) << 16);
    *(uint4*)(xb + (size_t)i * 8) = o;
}

// ---------------- weight pack: fragment-ready bf16 layout ----------------
__global__ __launch_bounds__(256) void packw_kernel(const float* __restrict__ Wl0, const float* __restrict__ Wr0,
                                                    const float* __restrict__ Wl1, const float* __restrict__ Wr1,
                                                    const float* __restrict__ Wl2, const float* __restrict__ Wr2,
                                                    unsigned short* __restrict__ Bp) {
    int idx = blockIdx.x * 256 + threadIdx.x;
    if (idx >= 12288) return;
    int g = idx & 3, c = (idx >> 2) & 127, s = (idx >> 9) & 3, t = (idx >> 11) & 1, L = idx >> 12;
    const float* W = (t == 0) ? (L == 0 ? Wl0 : (L == 1 ? Wl1 : Wl2))
                              : (L == 0 ? Wr0 : (L == 1 ? Wr1 : Wr2));
    int k0 = s * 32 + g * 8;
    uint4 o;
    o.x = f2bf(W[(k0 + 0) * 128 + c]) | ((unsigned)f2bf(W[(k0 + 1) * 128 + c]) << 16);
    o.y = f2bf(W[(k0 + 2) * 128 + c]) | ((unsigned)f2bf(W[(k0 + 3) * 128 + c]) << 16);
    o.z = f2bf(W[(k0 + 4) * 128 + c]) | ((unsigned)f2bf(W[(k0 + 5) * 128 + c]) << 16);
    o.w = f2bf(W[(k0 + 6) * 128 + c]) | ((unsigned)f2bf(W[(k0 + 7) * 128 + c]) << 16);
    size_t chunk = (((size_t)(L * 2 + t) * 4 + s) * 128 + c) * 4 + g;
    *(uint4*)(Bp + chunk * 8) = o;
}

// ---------------- CSR build: atomic-free bucket sort ----------------

// A1: per-chunk bin histogram -> cntMat[chunk][bin]
__global__ __launch_bounds__(256) void binhist_kernel(const int* __restrict__ dst,
                                                      int* __restrict__ cntMat, int E) {
    __shared__ int lcnt[512];
    const int tid = threadIdx.x;
    lcnt[tid] = 0; lcnt[tid + 256] = 0;
    __syncthreads();
    int base = blockIdx.x * CHUNK;
    int end = base + CHUNK; if (end > E) end = E;
    for (int i = base + tid; i < end; i += 256) atomicAdd(&lcnt[dst[i] >> 8], 1);
    __syncthreads();
    for (int j = tid; j < NBINS; j += 256) cntMat[(size_t)blockIdx.x * NBINS + j] = lcnt[j];
}

// A2a: per-bin column scan over chunks (one block per bin)
__global__ __launch_bounds__(512) void colscan_kernel(int* __restrict__ cntMat,
                                                      int* __restrict__ binCnt, int nch) {
    __shared__ int wsum[8];
    const int j = blockIdx.x;           // bin
    const int tid = threadIdx.x;
    const int lane = tid & 63, w = tid >> 6;
    int v = (tid < nch) ? cntMat[(size_t)tid * NBINS + j] : 0;
    int s = v;
    #pragma unroll
    for (int o = 1; o < 64; o <<= 1) {
        int t = __shfl_up(s, o, 64);
        if (lane >= o) s += t;
    }
    if (lane == 63) wsum[w] = s;
    __syncthreads();
    if (w == 0 && lane < 8) {
        int t = wsum[lane];
        int ss = t;
        #pragma unroll
        for (int o = 1; o < 8; o <<= 1) {
            int u = __shfl_up(ss, o, 64);
            if (lane >= o) ss += u;
        }
        wsum[lane] = ss - t;
    }
    __syncthreads();
    int excl = (s - v) + wsum[w];
    if (tid < nch) cntMat[(size_t)tid * NBINS + j] = excl;
    if (tid == 511) binCnt[j] = excl + v;   // column total (v=0 past nch)
}

// A2b: exclusive scan of bin totals -> binBase
__global__ __launch_bounds__(512) void binbase_kernel(const int* __restrict__ binCnt,
                                                      int* __restrict__ binBase,
                                                      int* __restrict__ offs, int E) {
    __shared__ int wsum[8];
    const int tid = threadIdx.x;
    const int lane = tid & 63, w = tid >> 6;
    int v = (tid < NBINS) ? binCnt[tid] : 0;
    int s = v;
    #pragma unroll
    for (int o = 1; o < 64; o <<= 1) {
        int t = __shfl_up(s, o, 64);
        if (lane >= o) s += t;
    }
    if (lane == 63) wsum[w] = s;
    __syncthreads();
    if (w == 0 && lane < 8) {
        int t = wsum[lane];
        int ss = t;
        #pragma unroll
        for (int o = 1; o < 8; o <<= 1) {
            int u = __shfl_up(ss, o, 64);
            if (lane >= o) ss += u;
        }
        wsum[lane] = ss - t;
    }
    __syncthreads();
    if (tid < NBINS) binBase[tid] = (s - v) + wsum[w];
    if (tid == 0) offs[N_NODES] = E;
}

// A3: scatter edges into bin regions (packed src | dstLow<<20); cursor = chunk-offset + binBase
__global__ __launch_bounds__(256) void binscat_kernel(const int* __restrict__ src, const int* __restrict__ dst,
                                                      const int* __restrict__ cntMat,
                                                      const int* __restrict__ binBase,
                                                      unsigned* __restrict__ binned, int E) {
    __shared__ int cur[512];
    const int tid = threadIdx.x;
    const int row = blockIdx.x;
    for (int j = tid; j < NBINS; j += 256) cur[j] = cntMat[(size_t)row * NBINS + j] + binBase[j];
    __syncthreads();
    int base = row * CHUNK;
    int end = base + CHUNK; if (end > E) end = E;
    for (int i = base + tid; i < end; i += 256) {
        int d = dst[i];
        int s = src[i];
        int bin = d >> 8;
        int pos = atomicAdd(&cur[bin], 1);
        binned[pos] = (unsigned)s | ((unsigned)(d & 255) << 20);
    }
}

// B: per-bin CSR finalize: offs + dst-sorted esrc (LDS-staged, coalesced out)
__global__ __launch_bounds__(256) void bincsr_kernel(const unsigned* __restrict__ binned,
                                                     const int* __restrict__ binBase, const int* __restrict__ binCnt,
                                                     int* __restrict__ esrc, int* __restrict__ offs) {
    __shared__ int h[256];
    __shared__ int cur[256];
    __shared__ int ssrc[8192];
    const int tid = threadIdx.x;
    const int bin = blockIdx.x;
    const int base = binBase[bin];
    const int cnt = binCnt[bin];
    h[tid] = 0;
    __syncthreads();
    for (int i = tid; i < cnt; i += 256) atomicAdd(&h[binned[base + i] >> 20], 1);
    __syncthreads();
    int v = h[tid];
    for (int o = 1; o < 256; o <<= 1) {
        int t = (tid >= o) ? h[tid - o] : 0;
        __syncthreads();
        h[tid] += t;
        __syncthreads();
    }
    int excl = h[tid] - v;
    cur[tid] = excl;
    int node = (bin << 8) + tid;
    if (node < N_NODES) offs[node] = base + excl;
    __syncthreads();
    for (int i = tid; i < cnt; i += 256) {
        unsigned p = binned[base + i];
        int pos = atomicAdd(&cur[p >> 20], 1);
        int s = (int)(p & 0xFFFFFu);
        if (pos < 8192) ssrc[pos] = s;
        else esrc[base + pos] = s;   // overflow fallback (never hit for uniform graph)
    }
    __syncthreads();
    int lim = cnt < 8192 ? cnt : 8192;
    for (int i = tid; i < lim; i += 256) esrc[base + i] = ssrc[i];
}

// ---------------- mean aggregation (bf16 rows, fp32 accumulate) ----------------
__global__ __launch_bounds__(256) void agg_kernel(const unsigned short* __restrict__ h,
                                                  const int* __restrict__ offs,
                                                  const int* __restrict__ esrc,
                                                  unsigned short* __restrict__ mean) {
    const int lane = threadIdx.x & 63;
    const int node = blockIdx.x * 4 + (threadIdx.x >> 6);
    const int beg = offs[node], end = offs[node + 1];
    const int nb = end - beg;
    float ax = 0.f, ay = 0.f;
    for (int base = 0; base < nb; base += 64) {
        int m = nb - base; if (m > 64) m = 64;
        int sv = (lane < m) ? esrc[beg + base + lane] : 0;
        int j = 0;
        for (; j + 4 <= m; j += 4) {
            int s0 = __shfl(sv, j, 64), s1 = __shfl(sv, j + 1, 64);
            int s2 = __shfl(sv, j + 2, 64), s3 = __shfl(sv, j + 3, 64);
            unsigned v0 = *(const unsigned*)(h + (size_t)s0 * HID + lane * 2);
            unsigned v1 = *(const unsigned*)(h + (size_t)s1 * HID + lane * 2);
            unsigned v2 = *(const unsigned*)(h + (size_t)s2 * HID + lane * 2);
            unsigned v3 = *(const unsigned*)(h + (size_t)s3 * HID + lane * 2);
            ax += bflo(v0) + bflo(v1) + bflo(v2) + bflo(v3);
            ay += bfhi(v0) + bfhi(v1) + bfhi(v2) + bfhi(v3);
        }
        for (; j < m; ++j) {
            int s0 = __shfl(sv, j, 64);
            unsigned v0 = *(const unsigned*)(h + (size_t)s0 * HID + lane * 2);
            ax += bflo(v0); ay += bfhi(v0);
        }
    }
    float inv = 1.f / (float)(nb > 0 ? nb : 1);
    *(unsigned*)(mean + (size_t)node * HID + lane * 2) =
        (unsigned)f2bf(ax * inv) | ((unsigned)f2bf(ay * inv) << 16);
}

// ---------------- MFMA GEMM: out = relu([mean|h]@[Wl;Wr] + b); score (+)= out@Wsl ----------------
__global__ __launch_bounds__(256) void gemm_kernel(const unsigned short* __restrict__ Am,
                                                   const unsigned short* __restrict__ Ah,
                                                   const unsigned short* __restrict__ Bp,
                                                   const float* __restrict__ bias,
                                                   const float* __restrict__ Wsl,
                                                   unsigned short* __restrict__ hout,
                                                   float* __restrict__ score,
                                                   const int accum, const int writeH) {
    __shared__ unsigned short At[2 * 64 * 128];
    __shared__ float sred[2][64];
    const int tid = threadIdx.x;
    const int lane = tid & 63;
    const int w = tid >> 6;
    const int wm = w & 1, wn = w >> 1;
    const int rowBase = blockIdx.x * 64;
    const int halfRow = lane & 15;
    const int g = lane >> 4;

    {
        const unsigned short* srcs[2] = { Am, Ah };
        #pragma unroll
        for (int r = 0; r < 8; ++r) {
            int c = r * 256 + tid;
            int sIdx = c >> 10;
            int rem = c & 1023;
            int row = rem >> 4, slot = rem & 15;
            int gslot = slot ^ (row & 15);
            int grow = rowBase + row; if (grow >= N_NODES) grow = N_NODES - 1;
            const unsigned short* gp = srcs[sIdx] + (size_t)grow * HID + gslot * 8;
            unsigned ldsOff = (unsigned)(r * 4096 + w * 1024);
            __builtin_amdgcn_global_load_lds((const __attribute__((address_space(1))) void*)gp,
                                             (__attribute__((address_space(3))) void*)((char*)At + ldsOff),
                                             16, 0, 0);
        }
    }
    __syncthreads();

    floatx4 acc[2][4];
    #pragma unroll
    for (int m = 0; m < 2; m++)
        #pragma unroll
        for (int n = 0; n < 4; n++) acc[m][n] = (floatx4){0.f, 0.f, 0.f, 0.f};

    #pragma unroll
    for (int t = 0; t < 2; t++) {
        #pragma unroll
        for (int s = 0; s < 4; s++) {
            int slot = (s * 4 + g) ^ halfRow;
            int row0 = wm * 32 + halfRow;
            short8v a0 = *(const short8v*)&At[t * 8192 + row0 * 128 + slot * 8];
            short8v a1 = *(const short8v*)&At[t * 8192 + (row0 + 16) * 128 + slot * 8];
            #pragma unroll
            for (int n = 0; n < 4; n++) {
                int col = wn * 64 + n * 16 + halfRow;
                short8v b = *(const short8v*)&Bp[((((size_t)(t * 4 + s)) * 128 + col) * 4 + g) * 8];
                acc[0][n] = __builtin_amdgcn_mfma_f32_16x16x32_bf16(a0, b, acc[0][n], 0, 0, 0);
                acc[1][n] = __builtin_amdgcn_mfma_f32_16x16x32_bf16(a1, b, acc[1][n], 0, 0, 0);
            }
        }
    }

    #pragma unroll
    for (int m = 0; m < 2; m++) {
        #pragma unroll
        for (int i = 0; i < 4; i++) {
            int rloc = wm * 32 + m * 16 + g * 4 + i;
            int grow = rowBase + rloc;
            float ps = 0.f;
            #pragma unroll
            for (int n = 0; n < 4; n++) {
                int col = wn * 64 + n * 16 + halfRow;
                float v = acc[m][n][i] + bias[col];
                v = fmaxf(v, 0.f);
                if (writeH && grow < N_NODES) hout[(size_t)grow * HID + col] = f2bf(v);
                ps += v * Wsl[col];
            }
            ps += __shfl_xor(ps, 1, 64);
            ps += __shfl_xor(ps, 2, 64);
            ps += __shfl_xor(ps, 4, 64);
            ps += __shfl_xor(ps, 8, 64);
            if (halfRow == 0) sred[wn][rloc] = ps;
        }
    }
    __syncthreads();
    if (w == 0) {
        int grow = rowBase + lane;
        if (grow < N_NODES) {
            float tot = sred[0][lane] + sred[1][lane];
            score[grow] = accum ? (score[grow] + tot) : tot;
        }
    }
}

// ---------------- finalize ----------------
__global__ __launch_bounds__(256) void finalize_kernel(const float* __restrict__ rr, const float* __restrict__ score,
                                                       const float* __restrict__ bs, const float* __restrict__ alpha,
                                                       float* __restrict__ out, int N) {
    int i = blockIdx.x * 256 + threadIdx.x;
    if (i < N) {
        float a = 1.f / (1.f + __expf(-alpha[0]));
        out[i] = a * rr[i] + (1.f - a) * (score[i] + bs[0]);
    }
}

extern "C" void kernel_launch(void* const* d_in, const int* in_sizes, int n_in,
                              void* d_out, int out_size, void* d_ws, size_t ws_size,
                              hipStream_t stream) {
    const float* x     = (const float*)d_in[0];
    const int*   eidx  = (const int*)d_in[1];
    const float* rrs   = (const float*)d_in[2];
    const float* Wl0   = (const float*)d_in[3];
    const float* Wr0   = (const float*)d_in[4];
    const float* b0    = (const float*)d_in[5];
    const float* Wl1   = (const float*)d_in[6];
    const float* Wr1   = (const float*)d_in[7];
    const float* b1    = (const float*)d_in[8];
    const float* Wl2   = (const float*)d_in[9];
    const float* Wr2   = (const float*)d_in[10];
    const float* b2    = (const float*)d_in[11];
    const float* Ws    = (const float*)d_in[12];
    const float* bs    = (const float*)d_in[13];
    const float* alpha = (const float*)d_in[14];

    const int N = N_NODES;
    const int E = in_sizes[1] / 2;
    const int* src = eidx;
    const int* dst = eidx + E;

    uintptr_t p = (uintptr_t)d_ws;
    auto alloc = [&](size_t bytes) -> void* {
        p = (p + 255) & ~(uintptr_t)255;
        void* r = (void*)p;
        p += bytes;
        return r;
    };
    int*            offs    = (int*)alloc((size_t)(N + 1) * 4);
    int*            esrc    = (int*)alloc((size_t)E * 4);
    float*          score   = (float*)alloc((size_t)N * 4);
    int*            binBase = (int*)alloc(512 * 4);
    int*            binCnt  = (int*)alloc(512 * 4);
    unsigned short* xb      = (unsigned short*)alloc((size_t)N * HID * 2);
    unsigned short* bufA    = (unsigned short*)alloc((size_t)N * HID * 2);
    unsigned short* bufB    = (unsigned short*)alloc((size_t)N * HID * 2);
    unsigned short* Bp      = (unsigned short*)alloc((size_t)3 * 32768 * 2);

    // dead-region aliases during CSR build (consumed before bufA/bufB are first written)
    int*      cntMat = (int*)bufA;        // nch*NBINS ints  (~612 KB)
    unsigned* binned = (unsigned*)bufB;   // E unsigneds     (6.4 MB)

    const int nch = (E + CHUNK - 1) / CHUNK;   // 391 (must be <= 512)

    // conversions
    convx_kernel<<<6250, 256, 0, stream>>>(x, xb, N * HID / 8);
    packw_kernel<<<48, 256, 0, stream>>>(Wl0, Wr0, Wl1, Wr1, Wl2, Wr2, Bp);

    // CSR build (atomic-free bucket sort, fully parallel scans)
    binhist_kernel<<<nch, 256, 0, stream>>>(dst, cntMat, E);
    colscan_kernel<<<NBINS, 512, 0, stream>>>(cntMat, binCnt, nch);
    binbase_kernel<<<1, 512, 0, stream>>>(binCnt, binBase, offs, E);
    binscat_kernel<<<nch, 256, 0, stream>>>(src, dst, cntMat, binBase, binned, E);
    bincsr_kernel<<<NBINS, 256, 0, stream>>>(binned, binBase, binCnt, esrc, offs);

    const int aggGrid  = N / 4;            // 25000
    const int gemmGrid = (N + 63) / 64;    // 1563

    // layer 0
    agg_kernel<<<aggGrid, 256, 0, stream>>>(xb, offs, esrc, bufA);
    gemm_kernel<<<gemmGrid, 256, 0, stream>>>(bufA, xb, Bp + 0 * 32768, b0, Ws + 0 * HID, bufA, score, 0, 1);
    // layer 1
    agg_kernel<<<aggGrid, 256, 0, stream>>>(bufA, offs, esrc, bufB);
    gemm_kernel<<<gemmGrid, 256, 0, stream>>>(bufB, bufA, Bp + 1 * 32768, b1, Ws + 1 * HID, bufB, score, 1, 1);
    // layer 2
    agg_kernel<<<aggGrid, 256, 0, stream>>>(bufB, offs, esrc, bufA);
    gemm_kernel<<<gemmGrid, 256, 0, stream>>>(bufA, bufB, Bp + 2 * 32768, b2, Ws + 2 * HID, bufA, score, 1, 0);

    finalize_kernel<<<(N + 255) / 256, 256, 0, stream>>>(rrs, score, bs, alpha, (float*)d_out, N);
}

// Round 5
// 317.959 us; speedup vs baseline: 3.4986x; 1.0024x over previous
//
#include <hip/hip_runtime.h>
#include <hip/hip_bf16.h>
#include <cstdint>

#define N_NODES 100000
#define HID 128
#define NBINS 391            // ceil(100000/256)
#define CHUNK 4096

typedef __attribute__((ext_vector_type(8))) short short8v;
typedef __attribute__((ext_vector_type(4))) float floatx4;

__device__ __forceinline__ float bflo(unsigned v) { return __uint_as_float(v << 16); }
__device__ __forceinline__ float bfhi(unsigned v) { return __uint_as_float(v & 0xffff0000u); }
__device__ __forceinline__ unsigned short f2bf(float f) {
    unsigned u = __float_as_uint(f);
    unsigned r = (u + 0x7fffu + ((u >> 16) & 1u)) >> 16;
    return (unsigned short)r;
}

// ---------------- prep: fp32->bf16 convert (x) + weight pack, one launch ----------------
__global__ __launch_bounds__(256) void prep_kernel(const float* __restrict__ x,
                                                   unsigned short* __restrict__ xb, int total8,
                                                   const float* __restrict__ Wl0, const float* __restrict__ Wr0,
                                                   const float* __restrict__ Wl1, const float* __restrict__ Wr1,
                                                   const float* __restrict__ Wl2, const float* __restrict__ Wr2,
                                                   unsigned short* __restrict__ Bp) {
    if ((int)blockIdx.x < total8 / 256) {
        int i = blockIdx.x * 256 + threadIdx.x;
        const float4* p = (const float4*)x + (size_t)i * 2;
        float4 a = p[0], b = p[1];
        uint4 o;
        o.x = f2bf(a.x) | ((unsigned)f2bf(a.y) << 16);
        o.y = f2bf(a.z) | ((unsigned)f2bf(a.w) << 16);
        o.z = f2bf(b.x) | ((unsigned)f2bf(b.y) << 16);
        o.w = f2bf(b.z) | ((unsigned)f2bf(b.w) << 16);
        *(uint4*)(xb + (size_t)i * 8) = o;
    } else {
        int idx = ((int)blockIdx.x - total8 / 256) * 256 + threadIdx.x;
        if (idx >= 12288) return;
        int g = idx & 3, c = (idx >> 2) & 127, s = (idx >> 9) & 3, t = (idx >> 11) & 1, L = idx >> 12;
        const float* W = (t == 0) ? (L == 0 ? Wl0 : (L == 1 ? Wl1 : Wl2))
                                  : (L == 0 ? Wr0 : (L == 1 ? Wr1 : Wr2));
        int k0 = s * 32 + g * 8;
        uint4 o;
        o.x = f2bf(W[(k0 + 0) * 128 + c]) | ((unsigned)f2bf(W[(k0 + 1) * 128 + c]) << 16);
        o.y = f2bf(W[(k0 + 2) * 128 + c]) | ((unsigned)f2bf(W[(k0 + 3) * 128 + c]) << 16);
        o.z = f2bf(W[(k0 + 4) * 128 + c]) | ((unsigned)f2bf(W[(k0 + 5) * 128 + c]) << 16);
        o.w = f2bf(W[(k0 + 6) * 128 + c]) | ((unsigned)f2bf(W[(k0 + 7) * 128 + c]) << 16);
        size_t chunk = (((size_t)(L * 2 + t) * 4 + s) * 128 + c) * 4 + g;
        *(uint4*)(Bp + chunk * 8) = o;
    }
}

// ---------------- CSR build: atomic-free bucket sort ----------------

__global__ __launch_bounds__(256) void binhist_kernel(const int* __restrict__ dst,
                                                      int* __restrict__ cntMat, int E) {
    __shared__ int lcnt[512];
    const int tid = threadIdx.x;
    lcnt[tid] = 0; lcnt[tid + 256] = 0;
    __syncthreads();
    int base = blockIdx.x * CHUNK;
    int end = base + CHUNK; if (end > E) end = E;
    for (int i = base + tid; i < end; i += 256) atomicAdd(&lcnt[dst[i] >> 8], 1);
    __syncthreads();
    for (int j = tid; j < NBINS; j += 256) cntMat[(size_t)blockIdx.x * NBINS + j] = lcnt[j];
}

__global__ __launch_bounds__(512) void colscan_kernel(int* __restrict__ cntMat,
                                                      int* __restrict__ binCnt, int nch) {
    __shared__ int wsum[8];
    const int j = blockIdx.x;
    const int tid = threadIdx.x;
    const int lane = tid & 63, w = tid >> 6;
    int v = (tid < nch) ? cntMat[(size_t)tid * NBINS + j] : 0;
    int s = v;
    #pragma unroll
    for (int o = 1; o < 64; o <<= 1) {
        int t = __shfl_up(s, o, 64);
        if (lane >= o) s += t;
    }
    if (lane == 63) wsum[w] = s;
    __syncthreads();
    if (w == 0 && lane < 8) {
        int t = wsum[lane];
        int ss = t;
        #pragma unroll
        for (int o = 1; o < 8; o <<= 1) {
            int u = __shfl_up(ss, o, 64);
            if (lane >= o) ss += u;
        }
        wsum[lane] = ss - t;
    }
    __syncthreads();
    int excl = (s - v) + wsum[w];
    if (tid < nch) cntMat[(size_t)tid * NBINS + j] = excl;
    if (tid == 511) binCnt[j] = excl + v;
}

__global__ __launch_bounds__(512) void binbase_kernel(const int* __restrict__ binCnt,
                                                      int* __restrict__ binBase,
                                                      int* __restrict__ offs, int E) {
    __shared__ int wsum[8];
    const int tid = threadIdx.x;
    const int lane = tid & 63, w = tid >> 6;
    int v = (tid < NBINS) ? binCnt[tid] : 0;
    int s = v;
    #pragma unroll
    for (int o = 1; o < 64; o <<= 1) {
        int t = __shfl_up(s, o, 64);
        if (lane >= o) s += t;
    }
    if (lane == 63) wsum[w] = s;
    __syncthreads();
    if (w == 0 && lane < 8) {
        int t = wsum[lane];
        int ss = t;
        #pragma unroll
        for (int o = 1; o < 8; o <<= 1) {
            int u = __shfl_up(ss, o, 64);
            if (lane >= o) ss += u;
        }
        wsum[lane] = ss - t;
    }
    __syncthreads();
    if (tid < NBINS) binBase[tid] = (s - v) + wsum[w];
    if (tid == 0) offs[N_NODES] = E;
}

__global__ __launch_bounds__(256) void binscat_kernel(const int* __restrict__ src, const int* __restrict__ dst,
                                                      const int* __restrict__ cntMat,
                                                      const int* __restrict__ binBase,
                                                      unsigned* __restrict__ binned, int E) {
    __shared__ int cur[512];
    const int tid = threadIdx.x;
    const int row = blockIdx.x;
    for (int j = tid; j < NBINS; j += 256) cur[j] = cntMat[(size_t)row * NBINS + j] + binBase[j];
    __syncthreads();
    int base = row * CHUNK;
    int end = base + CHUNK; if (end > E) end = E;
    for (int i = base + tid; i < end; i += 256) {
        int d = dst[i];
        int s = src[i];
        int bin = d >> 8;
        int pos = atomicAdd(&cur[bin], 1);
        binned[pos] = (unsigned)s | ((unsigned)(d & 255) << 20);
    }
}

__global__ __launch_bounds__(256) void bincsr_kernel(const unsigned* __restrict__ binned,
                                                     const int* __restrict__ binBase, const int* __restrict__ binCnt,
                                                     int* __restrict__ esrc, int* __restrict__ offs) {
    __shared__ int h[256];
    __shared__ int cur[256];
    __shared__ int ssrc[8192];
    const int tid = threadIdx.x;
    const int bin = blockIdx.x;
    const int base = binBase[bin];
    const int cnt = binCnt[bin];
    h[tid] = 0;
    __syncthreads();
    for (int i = tid; i < cnt; i += 256) atomicAdd(&h[binned[base + i] >> 20], 1);
    __syncthreads();
    int v = h[tid];
    for (int o = 1; o < 256; o <<= 1) {
        int t = (tid >= o) ? h[tid - o] : 0;
        __syncthreads();
        h[tid] += t;
        __syncthreads();
    }
    int excl = h[tid] - v;
    cur[tid] = excl;
    int node = (bin << 8) + tid;
    if (node < N_NODES) offs[node] = base + excl;
    __syncthreads();
    for (int i = tid; i < cnt; i += 256) {
        unsigned p = binned[base + i];
        int pos = atomicAdd(&cur[p >> 20], 1);
        int s = (int)(p & 0xFFFFFu);
        if (pos < 8192) ssrc[pos] = s;
        else esrc[base + pos] = s;
    }
    __syncthreads();
    int lim = cnt < 8192 ? cnt : 8192;
    for (int i = tid; i < lim; i += 256) esrc[base + i] = ssrc[i];
}

// ---------------- mean aggregation: uint2/lane, 2 rows per load, 16 rows in flight ----------------
__global__ __launch_bounds__(256) void agg_kernel(const unsigned short* __restrict__ h,
                                                  const int* __restrict__ offs,
                                                  const int* __restrict__ esrc,
                                                  unsigned short* __restrict__ mean) {
    const int lane = threadIdx.x & 63;
    const int node = blockIdx.x * 4 + (threadIdx.x >> 6);
    const int half = lane >> 5;     // 0: even row of pair, 1: odd row
    const int fl = lane & 31;       // features 4*fl .. 4*fl+3
    const int beg = offs[node], end = offs[node + 1];
    const int nb = end - beg;
    float a0 = 0.f, a1 = 0.f, a2 = 0.f, a3 = 0.f;
    for (int base = 0; base < nb; base += 64) {
        int m = nb - base; if (m > 64) m = 64;
        int sv = (lane < m) ? esrc[beg + base + lane] : 0;
        int j = 0;
        for (; j + 16 <= m; j += 16) {
            uint2 v[8];
            #pragma unroll
            for (int p = 0; p < 8; ++p) {
                int s = __shfl(sv, j + 2 * p + half, 64);
                v[p] = *(const uint2*)(h + (size_t)s * HID + fl * 4);
            }
            #pragma unroll
            for (int p = 0; p < 8; ++p) {
                a0 += bflo(v[p].x); a1 += bfhi(v[p].x);
                a2 += bflo(v[p].y); a3 += bfhi(v[p].y);
            }
        }
        for (; j + 2 <= m; j += 2) {
            int s = __shfl(sv, j + half, 64);
            uint2 vv = *(const uint2*)(h + (size_t)s * HID + fl * 4);
            a0 += bflo(vv.x); a1 += bfhi(vv.x);
            a2 += bflo(vv.y); a3 += bfhi(vv.y);
        }
        if (j < m) {
            int s = __shfl(sv, j, 64);
            if (half == 0) {
                uint2 vv = *(const uint2*)(h + (size_t)s * HID + fl * 4);
                a0 += bflo(vv.x); a1 += bfhi(vv.x);
                a2 += bflo(vv.y); a3 += bfhi(vv.y);
            }
        }
    }
    a0 += __shfl_xor(a0, 32, 64);
    a1 += __shfl_xor(a1, 32, 64);
    a2 += __shfl_xor(a2, 32, 64);
    a3 += __shfl_xor(a3, 32, 64);
    if (half == 0) {
        float inv = 1.f / (float)(nb > 0 ? nb : 1);
        uint2 o;
        o.x = (unsigned)f2bf(a0 * inv) | ((unsigned)f2bf(a1 * inv) << 16);
        o.y = (unsigned)f2bf(a2 * inv) | ((unsigned)f2bf(a3 * inv) << 16);
        *(uint2*)(mean + (size_t)node * HID + fl * 4) = o;
    }
}

// ---------------- MFMA GEMM: out = relu([mean|h]@[Wl;Wr] + b); score (+)= out@Wsl ----------------
// doFinal: fuse final blend  out = a*rr + (1-a)*(score_total + bs)
__global__ __launch_bounds__(256) void gemm_kernel(const unsigned short* __restrict__ Am,
                                                   const unsigned short* __restrict__ Ah,
                                                   const unsigned short* __restrict__ Bp,
                                                   const float* __restrict__ bias,
                                                   const float* __restrict__ Wsl,
                                                   unsigned short* __restrict__ hout,
                                                   float* __restrict__ score,
                                                   const float* __restrict__ rrs,
                                                   const float* __restrict__ bsp,
                                                   const float* __restrict__ alphap,
                                                   float* __restrict__ outF,
                                                   const int accum, const int writeH, const int doFinal) {
    __shared__ unsigned short At[2 * 64 * 128];
    __shared__ float sred[2][64];
    const int tid = threadIdx.x;
    const int lane = tid & 63;
    const int w = tid >> 6;
    const int wm = w & 1, wn = w >> 1;
    const int rowBase = blockIdx.x * 64;
    const int halfRow = lane & 15;
    const int g = lane >> 4;

    {
        const unsigned short* srcs[2] = { Am, Ah };
        #pragma unroll
        for (int r = 0; r < 8; ++r) {
            int c = r * 256 + tid;
            int sIdx = c >> 10;
            int rem = c & 1023;
            int row = rem >> 4, slot = rem & 15;
            int gslot = slot ^ (row & 15);
            int grow = rowBase + row; if (grow >= N_NODES) grow = N_NODES - 1;
            const unsigned short* gp = srcs[sIdx] + (size_t)grow * HID + gslot * 8;
            unsigned ldsOff = (unsigned)(r * 4096 + w * 1024);
            __builtin_amdgcn_global_load_lds((const __attribute__((address_space(1))) void*)gp,
                                             (__attribute__((address_space(3))) void*)((char*)At + ldsOff),
                                             16, 0, 0);
        }
    }
    __syncthreads();

    floatx4 acc[2][4];
    #pragma unroll
    for (int m = 0; m < 2; m++)
        #pragma unroll
        for (int n = 0; n < 4; n++) acc[m][n] = (floatx4){0.f, 0.f, 0.f, 0.f};

    #pragma unroll
    for (int t = 0; t < 2; t++) {
        #pragma unroll
        for (int s = 0; s < 4; s++) {
            int slot = (s * 4 + g) ^ halfRow;
            int row0 = wm * 32 + halfRow;
            short8v a0 = *(const short8v*)&At[t * 8192 + row0 * 128 + slot * 8];
            short8v a1 = *(const short8v*)&At[t * 8192 + (row0 + 16) * 128 + slot * 8];
            #pragma unroll
            for (int n = 0; n < 4; n++) {
                int col = wn * 64 + n * 16 + halfRow;
                short8v b = *(const short8v*)&Bp[((((size_t)(t * 4 + s)) * 128 + col) * 4 + g) * 8];
                acc[0][n] = __builtin_amdgcn_mfma_f32_16x16x32_bf16(a0, b, acc[0][n], 0, 0, 0);
                acc[1][n] = __builtin_amdgcn_mfma_f32_16x16x32_bf16(a1, b, acc[1][n], 0, 0, 0);
            }
        }
    }

    #pragma unroll
    for (int m = 0; m < 2; m++) {
        #pragma unroll
        for (int i = 0; i < 4; i++) {
            int rloc = wm * 32 + m * 16 + g * 4 + i;
            int grow = rowBase + rloc;
            float ps = 0.f;
            #pragma unroll
            for (int n = 0; n < 4; n++) {
                int col = wn * 64 + n * 16 + halfRow;
                float v = acc[m][n][i] + bias[col];
                v = fmaxf(v, 0.f);
                if (writeH && grow < N_NODES) hout[(size_t)grow * HID + col] = f2bf(v);
                ps += v * Wsl[col];
            }
            ps += __shfl_xor(ps, 1, 64);
            ps += __shfl_xor(ps, 2, 64);
            ps += __shfl_xor(ps, 4, 64);
            ps += __shfl_xor(ps, 8, 64);
            if (halfRow == 0) sred[wn][rloc] = ps;
        }
    }
    __syncthreads();
    if (w == 0) {
        int grow = rowBase + lane;
        if (grow < N_NODES) {
            float tot = sred[0][lane] + sred[1][lane];
            if (doFinal) {
                float sc = score[grow] + tot;
                float a = 1.f / (1.f + __expf(-alphap[0]));
                outF[grow] = a * rrs[grow] + (1.f - a) * (sc + bsp[0]);
            } else {
                score[grow] = accum ? (score[grow] + tot) : tot;
            }
        }
    }
}

extern "C" void kernel_launch(void* const* d_in, const int* in_sizes, int n_in,
                              void* d_out, int out_size, void* d_ws, size_t ws_size,
                              hipStream_t stream) {
    const float* x     = (const float*)d_in[0];
    const int*   eidx  = (const int*)d_in[1];
    const float* rrs   = (const float*)d_in[2];
    const float* Wl0   = (const float*)d_in[3];
    const float* Wr0   = (const float*)d_in[4];
    const float* b0    = (const float*)d_in[5];
    const float* Wl1   = (const float*)d_in[6];
    const float* Wr1   = (const float*)d_in[7];
    const float* b1    = (const float*)d_in[8];
    const float* Wl2   = (const float*)d_in[9];
    const float* Wr2   = (const float*)d_in[10];
    const float* b2    = (const float*)d_in[11];
    const float* Ws    = (const float*)d_in[12];
    const float* bs    = (const float*)d_in[13];
    const float* alpha = (const float*)d_in[14];

    const int N = N_NODES;
    const int E = in_sizes[1] / 2;
    const int* src = eidx;
    const int* dst = eidx + E;

    uintptr_t p = (uintptr_t)d_ws;
    auto alloc = [&](size_t bytes) -> void* {
        p = (p + 255) & ~(uintptr_t)255;
        void* r = (void*)p;
        p += bytes;
        return r;
    };
    int*            offs    = (int*)alloc((size_t)(N + 1) * 4);
    int*            esrc    = (int*)alloc((size_t)E * 4);
    float*          score   = (float*)alloc((size_t)N * 4);
    int*            binBase = (int*)alloc(512 * 4);
    int*            binCnt  = (int*)alloc(512 * 4);
    unsigned short* xb      = (unsigned short*)alloc((size_t)N * HID * 2);
    unsigned short* bufA    = (unsigned short*)alloc((size_t)N * HID * 2);
    unsigned short* bufB    = (unsigned short*)alloc((size_t)N * HID * 2);
    unsigned short* Bp      = (unsigned short*)alloc((size_t)3 * 32768 * 2);

    int*      cntMat = (int*)bufA;
    unsigned* binned = (unsigned*)bufB;

    const int nch = (E + CHUNK - 1) / CHUNK;   // 391

    prep_kernel<<<N * HID / 8 / 256 + 48, 256, 0, stream>>>(x, xb, N * HID / 8,
                                                            Wl0, Wr0, Wl1, Wr1, Wl2, Wr2, Bp);

    binhist_kernel<<<nch, 256, 0, stream>>>(dst, cntMat, E);
    colscan_kernel<<<NBINS, 512, 0, stream>>>(cntMat, binCnt, nch);
    binbase_kernel<<<1, 512, 0, stream>>>(binCnt, binBase, offs, E);
    binscat_kernel<<<nch, 256, 0, stream>>>(src, dst, cntMat, binBase, binned, E);
    bincsr_kernel<<<NBINS, 256, 0, stream>>>(binned, binBase, binCnt, esrc, offs);

    const int aggGrid  = N / 4;
    const int gemmGrid = (N + 63) / 64;
    float* outF = (float*)d_out;

    agg_kernel<<<aggGrid, 256, 0, stream>>>(xb, offs, esrc, bufA);
    gemm_kernel<<<gemmGrid, 256, 0, stream>>>(bufA, xb, Bp + 0 * 32768, b0, Ws + 0 * HID, bufA, score,
                                              rrs, bs, alpha, outF, 0, 1, 0);
    agg_kernel<<<aggGrid, 256, 0, stream>>>(bufA, offs, esrc, bufB);
    gemm_kernel<<<gemmGrid, 256, 0, stream>>>(bufB, bufA, Bp + 1 * 32768, b1, Ws + 1 * HID, bufB, score,
                                              rrs, bs, alpha, outF, 1, 1, 0);
    agg_kernel<<<aggGrid, 256, 0, stream>>>(bufB, offs, esrc, bufA);
    gemm_kernel<<<gemmGrid, 256, 0, stream>>>(bufA, bufB, Bp + 2 * 32768, b2, Ws + 2 * HID, bufA, score,
                                              rrs, bs, alpha, outF, 1, 0, 1);
}